// Round 1
// baseline (1489.895 us; speedup 1.0000x reference)
//
#include <hip/hip_runtime.h>
#include <cstddef>

#define B_  8
#define C_  256
#define H_  64
#define W_  64
#define HW_ 4096
#define NG_ 256   // 16x16 global tokens

__device__ __forceinline__ float sigm(float v) { return 1.f / (1.f + expf(-v)); }

// ---------------------------------------------------------------------------
// Generic tiled SGEMM: out[M,256] = sum_seg A_seg[M,256] @ W[seg*256:(seg+1)*256, 256]
// mode 0: + bias[n]
// mode 1: + bias[n] + pos[(m % NTOK)*256 + n]
// mode 2: + bbias[(m / NTOK)*256 + n]          (per-batch bias row)
// ---------------------------------------------------------------------------
__global__ __launch_bounds__(256) void gemm256(
    const float* __restrict__ A0, const float* __restrict__ A1, const float* __restrict__ A2,
    int nseg, const float* __restrict__ Wm, const float* __restrict__ bias,
    const float* __restrict__ pos, float* __restrict__ out, int M, int NTOK, int mode)
{
    __shared__ float As[16][68];
    __shared__ float Bs[16][68];
    const int tid = threadIdx.x;
    const int tx = tid & 15, ty = tid >> 4;
    const int m0 = blockIdx.x * 64;
    const int n0 = blockIdx.y * 64;
    float acc[4][4] = {};
    const int lmA = tid >> 2, lkA = (tid & 3) << 2;
    const int lkB = tid >> 4, lnB = (tid & 15) << 2;

    for (int seg = 0; seg < nseg; ++seg) {
        const float* __restrict__ A = (seg == 0) ? A0 : ((seg == 1) ? A1 : A2);
        for (int k0 = 0; k0 < 256; k0 += 16) {
            float4 av = *(const float4*)(A + (size_t)(m0 + lmA) * 256 + (k0 + lkA));
            As[lkA + 0][lmA] = av.x;
            As[lkA + 1][lmA] = av.y;
            As[lkA + 2][lmA] = av.z;
            As[lkA + 3][lmA] = av.w;
            *(float4*)(&Bs[lkB][lnB]) =
                *(const float4*)(Wm + (size_t)(seg * 256 + k0 + lkB) * 256 + n0 + lnB);
            __syncthreads();
#pragma unroll
            for (int kk = 0; kk < 16; ++kk) {
                float4 a4 = *(const float4*)(&As[kk][ty << 2]);
                float4 b4 = *(const float4*)(&Bs[kk][tx << 2]);
                float aa[4] = {a4.x, a4.y, a4.z, a4.w};
                float bb[4] = {b4.x, b4.y, b4.z, b4.w};
#pragma unroll
                for (int i = 0; i < 4; ++i)
#pragma unroll
                    for (int j = 0; j < 4; ++j)
                        acc[i][j] += aa[i] * bb[j];
            }
            __syncthreads();
        }
    }

#pragma unroll
    for (int i = 0; i < 4; ++i) {
        int m = m0 + (ty << 2) + i;
        int n = n0 + (tx << 2);
        float4 r;
        float* rp = &r.x;
#pragma unroll
        for (int j = 0; j < 4; ++j) {
            float v = acc[i][j];
            if (mode == 0)       v += bias[n + j];
            else if (mode == 1)  v += bias[n + j] + pos[(size_t)(m % NTOK) * 256 + n + j];
            else                 v += bias[(size_t)(m / NTOK) * 256 + n + j];
            rp[j] = v;
        }
        *(float4*)(out + (size_t)m * 256 + n) = r;
    }
}

// ---------------------------------------------------------------------------
// Transpose [B][R][Cc] -> [B][Cc][R].  grid (Cc/32, R/32, B), block (32,8)
// ---------------------------------------------------------------------------
__global__ __launch_bounds__(256) void transpose_k(const float* __restrict__ in,
                                                   float* __restrict__ out, int R, int Cc)
{
    __shared__ float t[32][33];
    int b = blockIdx.z;
    int r0 = blockIdx.y * 32, c0 = blockIdx.x * 32;
    int tx = threadIdx.x, ty = threadIdx.y;
    const float* ip = in + (size_t)b * R * Cc;
    float* op = out + (size_t)b * R * Cc;
#pragma unroll
    for (int k = 0; k < 32; k += 8)
        t[ty + k][tx] = ip[(size_t)(r0 + ty + k) * Cc + c0 + tx];
    __syncthreads();
#pragma unroll
    for (int k = 0; k < 32; k += 8)
        op[(size_t)(c0 + ty + k) * R + r0 + tx] = t[tx][ty + k];
}

// out[B][C][HW] = x + transpose(in [B][HW][C]).  grid (C/32, HW/32, B), block (32,8)
__global__ __launch_bounds__(256) void transpose_add_k(const float* __restrict__ in,
                                                       const float* __restrict__ x,
                                                       float* __restrict__ out)
{
    __shared__ float t[32][33];
    int b = blockIdx.z;
    int r0 = blockIdx.y * 32, c0 = blockIdx.x * 32;  // r = hw, c = channel
    int tx = threadIdx.x, ty = threadIdx.y;
    const float* ip = in + (size_t)b * HW_ * C_;
    const float* xp = x  + (size_t)b * HW_ * C_;
    float* op = out + (size_t)b * HW_ * C_;
#pragma unroll
    for (int k = 0; k < 32; k += 8)
        t[ty + k][tx] = ip[(size_t)(r0 + ty + k) * C_ + c0 + tx];
    __syncthreads();
#pragma unroll
    for (int k = 0; k < 32; k += 8) {
        size_t oi = (size_t)(c0 + ty + k) * HW_ + r0 + tx;
        op[oi] = xp[oi] + t[tx][ty + k];
    }
}

// ---------------------------------------------------------------------------
// 4x4 avg pool x[B][C][64][64] -> seq_g[B][256tok][C].  grid (B, C), block 256 = ghw
// ---------------------------------------------------------------------------
__global__ __launch_bounds__(256) void pool_k(const float* __restrict__ x, float* __restrict__ seqg)
{
    int b = blockIdx.x, c = blockIdx.y, ghw = threadIdx.x;
    int gh = ghw >> 4, gw = ghw & 15;
    const float* xp = x + ((size_t)b * C_ + c) * HW_;
    float s = 0.f;
#pragma unroll
    for (int dy = 0; dy < 4; ++dy)
#pragma unroll
        for (int dx = 0; dx < 4; ++dx)
            s += xp[(gh * 4 + dy) * W_ + gw * 4 + dx];
    seqg[((size_t)b * NG_ + ghw) * C_ + c] = s * (1.f / 16.f);
}

// pos_fine [1][256][32][32] -> posF[4096][256], half-pixel bilinear 2x (clamp == renorm)
__global__ __launch_bounds__(256) void posfine_k(const float* __restrict__ pf, float* __restrict__ posF)
{
    int hw = blockIdx.x, c = threadIdx.x;
    int h = hw >> 6, w = hw & 63;
    float fy = h * 0.5f - 0.25f, fx = w * 0.5f - 0.25f;
    int y0 = (int)floorf(fy); float wy = fy - (float)y0;
    int x0 = (int)floorf(fx); float wx = fx - (float)x0;
    int y0c = min(max(y0, 0), 31), y1c = min(max(y0 + 1, 0), 31);
    int x0c = min(max(x0, 0), 31), x1c = min(max(x0 + 1, 0), 31);
    const float* p = pf + (size_t)c * 1024;
    float v = (1.f - wy) * ((1.f - wx) * p[y0c * 32 + x0c] + wx * p[y0c * 32 + x1c])
            +        wy  * ((1.f - wx) * p[y1c * 32 + x0c] + wx * p[y1c * 32 + x1c]);
    posF[(size_t)hw * C_ + c] = v;
}

// pos_glob [1][256][32][32] -> posG[256][256]: antialiased 2x downsample (4-tap triangle)
__global__ __launch_bounds__(256) void posglob_k(const float* __restrict__ pg, float* __restrict__ posG)
{
    int ghw = blockIdx.x, c = threadIdx.x;
    int gh = ghw >> 4, gw = ghw & 15;
    const float wt[4] = {0.125f, 0.375f, 0.375f, 0.125f};
    float wy[4], wx[4]; int jy[4], jx[4];
    float sy = 0.f, sx = 0.f;
#pragma unroll
    for (int k = 0; k < 4; ++k) {
        jy[k] = 2 * gh - 1 + k; jx[k] = 2 * gw - 1 + k;
        wy[k] = (jy[k] >= 0 && jy[k] < 32) ? wt[k] : 0.f; sy += wy[k];
        wx[k] = (jx[k] >= 0 && jx[k] < 32) ? wt[k] : 0.f; sx += wx[k];
    }
    const float* p = pg + (size_t)c * 1024;
    float acc = 0.f;
#pragma unroll
    for (int ky = 0; ky < 4; ++ky) {
        if (wy[ky] == 0.f) continue;
        float row = 0.f;
#pragma unroll
        for (int kx = 0; kx < 4; ++kx)
            if (wx[kx] != 0.f) row += wx[kx] * p[jy[ky] * 32 + jx[kx]];
        acc += wy[ky] * row;
    }
    posG[(size_t)ghw * C_ + c] = acc / (sy * sx);
}

// y_g[B][256tok][C] -> y_g_seq[B][4096][C]: half-pixel bilinear 4x up (clamp == renorm)
__global__ __launch_bounds__(256) void upsample_k(const float* __restrict__ yg, float* __restrict__ ygs)
{
    int b = blockIdx.x >> 12, hw = blockIdx.x & 4095, c = threadIdx.x;
    int h = hw >> 6, w = hw & 63;
    float fy = h * 0.25f - 0.375f, fx = w * 0.25f - 0.375f;
    int y0 = (int)floorf(fy); float wy = fy - (float)y0;
    int x0 = (int)floorf(fx); float wx = fx - (float)x0;
    int y0c = min(max(y0, 0), 15), y1c = min(max(y0 + 1, 0), 15);
    int x0c = min(max(x0, 0), 15), x1c = min(max(x0 + 1, 0), 15);
    const float* p = yg + (size_t)b * NG_ * C_ + c;
    float v = (1.f - wy) * ((1.f - wx) * p[(y0c * 16 + x0c) * C_] + wx * p[(y0c * 16 + x1c) * C_])
            +        wy  * ((1.f - wx) * p[(y1c * 16 + x0c) * C_] + wx * p[(y1c * 16 + x1c) * C_]);
    ygs[((size_t)b * HW_ + hw) * C_ + c] = v;
}

// depthwise 3x3 SAME conv + bias -> vmap[B][C][HW].  grid (B*C, 16), block 256
__global__ __launch_bounds__(256) void dwconv_k(const float* __restrict__ x,
                                                const float* __restrict__ dww,
                                                const float* __restrict__ dwb,
                                                float* __restrict__ vmap)
{
    int bc = blockIdx.x;
    int hw = blockIdx.y * 256 + threadIdx.x;
    int c = bc & 255;
    int h = hw >> 6, w = hw & 63;
    const float* xp = x + (size_t)bc * HW_;
    const float* wp = dww + c * 9;
    float acc = dwb[c];
#pragma unroll
    for (int dy = 0; dy < 3; ++dy) {
        int hh = h + dy - 1;
        if (hh < 0 || hh > 63) continue;
#pragma unroll
        for (int dx = 0; dx < 3; ++dx) {
            int ww = w + dx - 1;
            if (ww < 0 || ww > 63) continue;
            acc += xp[hh * W_ + ww] * wp[dy * 3 + dx];
        }
    }
    vmap[(size_t)bc * HW_ + hw] = acc;
}

// partial token-mean: grid (B, S), block 256=c
__global__ __launch_bounds__(256) void meanpart_k(const float* __restrict__ u, float* __restrict__ part,
                                                  int Ntok, int chunkLen)
{
    int b = blockIdx.x, s = blockIdx.y, c = threadIdx.x;
    float acc = 0.f;
    for (int i = 0; i < chunkLen; ++i) {
        int t = s * chunkLen + i;
        acc += u[((size_t)b * Ntok + t) * C_ + c];
    }
    part[((size_t)b * gridDim.y + s) * C_ + c] = acc;
}

// finish mean + LayerNorm over C.  grid (B), block 256
__global__ __launch_bounds__(256) void ln_k(const float* __restrict__ part, int S, float invN,
                                            const float* __restrict__ g, const float* __restrict__ bta,
                                            float* __restrict__ cout)
{
    __shared__ float red[256];
    int c = threadIdx.x, b = blockIdx.x;
    float v = 0.f;
    for (int s = 0; s < S; ++s) v += part[((size_t)b * S + s) * C_ + c];
    v *= invN;
    red[c] = v; __syncthreads();
    for (int st = 128; st > 0; st >>= 1) { if (c < st) red[c] += red[c + st]; __syncthreads(); }
    float m = red[0] * (1.f / 256.f);
    __syncthreads();
    float d = v - m;
    red[c] = d * d; __syncthreads();
    for (int st = 128; st > 0; st >>= 1) { if (c < st) red[c] += red[c + st]; __syncthreads(); }
    float var = red[0] * (1.f / 256.f);
    cout[(size_t)b * C_ + c] = d * rsqrtf(var + 1e-5f) * g[c] + bta[c];
}

// per-batch gate bias rows: cf[gate][b][n] = c[b] @ Wg[256:,:] + bg.  grid (B, 3), block 256
__global__ __launch_bounds__(256) void gatebias_k(const float* __restrict__ cvec,
    const float* __restrict__ Wf, const float* __restrict__ bf,
    const float* __restrict__ Ww, const float* __restrict__ bw,
    const float* __restrict__ Wo, const float* __restrict__ bo,
    float* __restrict__ outb)
{
    int n = threadIdx.x, b = blockIdx.x, gate = blockIdx.y;
    const float* Wm = (gate == 0) ? Wf : ((gate == 1) ? Ww : Wo);
    const float* bi = (gate == 0) ? bf : ((gate == 1) ? bw : bo);
    __shared__ float cs[256];
    cs[n] = cvec[(size_t)b * C_ + n];
    __syncthreads();
    float acc = bi[n];
    for (int k = 0; k < 256; ++k)
        acc += cs[k] * Wm[(size_t)(256 + k) * C_ + n];
    outb[((size_t)gate * B_ + b) * C_ + n] = acc;
}

// gate activations in place: a = sigmoid(-dpre); bb = (1-a)*sigmoid(wpre)*u; o = sigmoid(opre)
__global__ __launch_bounds__(256) void gates_k(float* __restrict__ dpre, float* __restrict__ wpre,
                                               float* __restrict__ opre, const float* __restrict__ u)
{
    size_t i = (size_t)blockIdx.x * 256 + threadIdx.x;
    float d = dpre[i], wv = wpre[i], ov = opre[i], uv = u[i];
    float a = 1.f / (1.f + expf(d));          // exp(-softplus(d)) == sigmoid(-d)
    float g = sigm(wv);
    dpre[i] = a;
    wpre[i] = (1.f - a) * g * uv;
    opre[i] = sigm(ov);
}

// ---------------- chunked linear-recurrence scan -------------------------
// pass1: per-chunk composition (A = prod a, B = fold).  grid (B*nchunk), block 256=c
__global__ __launch_bounds__(256) void scan_p1(const float* __restrict__ a, const float* __restrict__ bb,
                                               float* __restrict__ Ab, float* __restrict__ Bb,
                                               int Ntok, int chunkLen, int nchunk, int backward)
{
    int c = threadIdx.x;
    int chunk = blockIdx.x % nchunk;
    int b = blockIdx.x / nchunk;
    float sA = 1.f, sB = 0.f;
    for (int i = 0; i < chunkLen; ++i) {
        int tp = chunk * chunkLen + i;
        int t = backward ? (Ntok - 1 - tp) : tp;
        size_t idx = ((size_t)b * Ntok + t) * C_ + c;
        float av = a[idx];
        sB = av * sB + bb[idx];
        sA *= av;
    }
    size_t o = ((size_t)b * nchunk + chunk) * C_ + c;
    Ab[o] = sA; Bb[o] = sB;
}

// pass2: sequential combine across chunks -> incoming state per chunk.  grid (B), block 256
__global__ __launch_bounds__(256) void scan_p2(const float* __restrict__ Ab, const float* __restrict__ Bb,
                                               float* __restrict__ Sb, int nchunk)
{
    int c = threadIdx.x, b = blockIdx.x;
    float s = 0.f;
    for (int ch = 0; ch < nchunk; ++ch) {
        size_t o = ((size_t)b * nchunk + ch) * C_ + c;
        Sb[o] = s;
        s = Ab[o] * s + Bb[o];
    }
}

// pass3: replay with correct incoming state, emit y.  grid (B*nchunk), block 256
__global__ __launch_bounds__(256) void scan_p3(const float* __restrict__ a, const float* __restrict__ bb,
                                               const float* __restrict__ o_, const float* __restrict__ u,
                                               const float* __restrict__ Sb, float* __restrict__ y,
                                               int Ntok, int chunkLen, int nchunk, int backward)
{
    int c = threadIdx.x;
    int chunk = blockIdx.x % nchunk;
    int b = blockIdx.x / nchunk;
    float s = Sb[((size_t)b * nchunk + chunk) * C_ + c];
    for (int i = 0; i < chunkLen; ++i) {
        int tp = chunk * chunkLen + i;
        int t = backward ? (Ntok - 1 - tp) : tp;
        size_t idx = ((size_t)b * Ntok + t) * C_ + c;
        float av = a[idx];
        s = av * s + bb[idx];
        float ov = o_[idx];
        y[idx] = ov * s + (1.f - ov) * u[idx];
    }
}

// ---------------- elementwise combiners ----------------------------------
__global__ __launch_bounds__(256) void combine_rho_k(float* __restrict__ rho_y,
                                                     const float* __restrict__ yf,
                                                     const float* __restrict__ yb)
{
    size_t i = (size_t)blockIdx.x * 256 + threadIdx.x;
    float r = sigm(rho_y[i]);
    rho_y[i] = r * yf[i] + (1.f - r) * yb[i];
}

__global__ __launch_bounds__(256) void zfuse_k(const float* __restrict__ y, const float* __restrict__ lam,
                                               const float* __restrict__ ygs, float* __restrict__ z)
{
    size_t i = (size_t)blockIdx.x * 256 + threadIdx.x;
    z[i] = y[i] + sigm(lam[i]) * ygs[i];
}

__global__ __launch_bounds__(256) void uout_k(const float* __restrict__ eta, const float* __restrict__ v,
                                              const float* __restrict__ z, float* __restrict__ uo)
{
    size_t i = (size_t)blockIdx.x * 256 + threadIdx.x;
    float e = sigm(eta[i]);
    uo[i] = e * v[i] + (1.f - e) * z[i];
}

// ===========================================================================
extern "C" void kernel_launch(void* const* d_in, const int* in_sizes, int n_in,
                              void* d_out, int out_size, void* d_ws, size_t ws_size,
                              hipStream_t stream)
{
    const float* x        = (const float*)d_in[0];
    const float* Wt       = (const float*)d_in[1];
    const float* bt       = (const float*)d_in[2];
    const float* pos_fine = (const float*)d_in[3];
    const float* pos_glob = (const float*)d_in[4];
    const float* ln_g     = (const float*)d_in[5];
    const float* ln_b     = (const float*)d_in[6];
    const float* Wf       = (const float*)d_in[7];
    const float* bf       = (const float*)d_in[8];
    const float* Ww       = (const float*)d_in[9];
    const float* bw       = (const float*)d_in[10];
    const float* Wo       = (const float*)d_in[11];
    const float* bo       = (const float*)d_in[12];
    const float* Wr       = (const float*)d_in[13];
    const float* br       = (const float*)d_in[14];
    const float* Wgi      = (const float*)d_in[15];
    const float* bgi      = (const float*)d_in[16];
    const float* dww      = (const float*)d_in[17];
    const float* dwb      = (const float*)d_in[18];
    const float* Wl       = (const float*)d_in[19];
    const float* bl       = (const float*)d_in[20];
    const float* Wlf      = (const float*)d_in[21];
    const float* blf      = (const float*)d_in[22];
    const float* Wout     = (const float*)d_in[23];
    const float* bout     = (const float*)d_in[24];
    float* out = (float*)d_out;

    float* w = (float*)d_ws;
    const size_t BNC = (size_t)B_ * HW_ * C_;        // 8,388,608 floats
    float* bu  = w + 0 * BNC;   // u
    float* ba  = w + 1 * BNC;   // dpre -> a -> rho_pre -> y -> u_out
    float* bbb = w + 2 * BNC;   // wpre -> bb -> lam_pre -> v
    float* bo_ = w + 3 * BNC;   // opre -> o -> z -> out_map
    float* byf = w + 4 * BNC;   // y_f -> vmap -> eta_pre
    float* byb = w + 5 * BNC;   // y_b -> vseq -> out_map staging
    float* bx6 = w + 6 * BNC;   // seq -> y_g_seq
    float* ext = w + 7 * BNC;
    float* posF = ext;  ext += (size_t)HW_ * C_;
    float* posG = ext;  ext += (size_t)NG_ * C_;
    float* part = ext;  ext += (size_t)B_ * 32 * C_;
    float* cln  = ext;  ext += (size_t)B_ * C_;
    float* cf   = ext;  ext += (size_t)3 * B_ * C_;
    float* seqg = ext;  ext += (size_t)B_ * NG_ * C_;
    float* ug   = ext;  ext += (size_t)B_ * NG_ * C_;
    float* ag   = ext;  ext += (size_t)B_ * NG_ * C_;
    float* bbg  = ext;  ext += (size_t)B_ * NG_ * C_;
    float* og   = ext;  ext += (size_t)B_ * NG_ * C_;
    float* ygt  = ext;  ext += (size_t)B_ * NG_ * C_;
    float* chA  = ext;  ext += (size_t)B_ * 64 * C_;
    float* chB  = ext;  ext += (size_t)B_ * 64 * C_;
    float* chS  = ext;  ext += (size_t)B_ * 64 * C_;

    const dim3 blk256(256);
    const dim3 blkT(32, 8);
    const int EW = (int)(BNC / 256);       // 32768 elementwise blocks
    const int EWG = (B_ * NG_ * C_) / 256; // 2048

    // ---- fine: seq + u ----------------------------------------------------
    transpose_k<<<dim3(HW_ / 32, C_ / 32, B_), blkT, 0, stream>>>(x, bx6, C_, HW_);
    posfine_k<<<HW_, blk256, 0, stream>>>(pos_fine, posF);
    gemm256<<<dim3(B_ * HW_ / 64, 4), blk256, 0, stream>>>(
        bx6, nullptr, nullptr, 1, Wt, bt, posF, bu, B_ * HW_, HW_, 1);
    // bx6 (seq) dead now

    // ---- global branch ----------------------------------------------------
    pool_k<<<dim3(B_, C_), blk256, 0, stream>>>(x, seqg);
    posglob_k<<<NG_, blk256, 0, stream>>>(pos_glob, posG);
    gemm256<<<dim3(B_ * NG_ / 64, 4), blk256, 0, stream>>>(
        seqg, nullptr, nullptr, 1, Wt, bt, posG, ug, B_ * NG_, NG_, 1);
    meanpart_k<<<dim3(B_, 8), blk256, 0, stream>>>(ug, part, NG_, 32);
    ln_k<<<B_, blk256, 0, stream>>>(part, 8, 1.f / NG_, ln_g, ln_b, cln);
    gatebias_k<<<dim3(B_, 3), blk256, 0, stream>>>(cln, Wf, bf, Ww, bw, Wo, bo, cf);
    gemm256<<<dim3(B_ * NG_ / 64, 4), blk256, 0, stream>>>(
        ug, nullptr, nullptr, 1, Wf, cf + 0 * B_ * C_, nullptr, ag, B_ * NG_, NG_, 2);
    gemm256<<<dim3(B_ * NG_ / 64, 4), blk256, 0, stream>>>(
        ug, nullptr, nullptr, 1, Ww, cf + 1 * B_ * C_, nullptr, bbg, B_ * NG_, NG_, 2);
    gemm256<<<dim3(B_ * NG_ / 64, 4), blk256, 0, stream>>>(
        ug, nullptr, nullptr, 1, Wo, cf + 2 * B_ * C_, nullptr, og, B_ * NG_, NG_, 2);
    gates_k<<<EWG, blk256, 0, stream>>>(ag, bbg, og, ug);
    scan_p1<<<B_ * 16, blk256, 0, stream>>>(ag, bbg, chA, chB, NG_, 16, 16, 0);
    scan_p2<<<B_, blk256, 0, stream>>>(chA, chB, chS, 16);
    scan_p3<<<B_ * 16, blk256, 0, stream>>>(ag, bbg, og, ug, chS, ygt, NG_, 16, 16, 0);
    upsample_k<<<B_ * HW_, blk256, 0, stream>>>(ygt, bx6);   // y_g_seq -> bx6

    // ---- fine: gates + bidirectional scans -------------------------------
    meanpart_k<<<dim3(B_, 32), blk256, 0, stream>>>(bu, part, HW_, 128);
    ln_k<<<B_, blk256, 0, stream>>>(part, 32, 1.f / HW_, ln_g, ln_b, cln);
    gatebias_k<<<dim3(B_, 3), blk256, 0, stream>>>(cln, Wf, bf, Ww, bw, Wo, bo, cf);
    gemm256<<<dim3(B_ * HW_ / 64, 4), blk256, 0, stream>>>(
        bu, nullptr, nullptr, 1, Wf, cf + 0 * B_ * C_, nullptr, ba, B_ * HW_, HW_, 2);
    gemm256<<<dim3(B_ * HW_ / 64, 4), blk256, 0, stream>>>(
        bu, nullptr, nullptr, 1, Ww, cf + 1 * B_ * C_, nullptr, bbb, B_ * HW_, HW_, 2);
    gemm256<<<dim3(B_ * HW_ / 64, 4), blk256, 0, stream>>>(
        bu, nullptr, nullptr, 1, Wo, cf + 2 * B_ * C_, nullptr, bo_, B_ * HW_, HW_, 2);
    gates_k<<<EW, blk256, 0, stream>>>(ba, bbb, bo_, bu);
    // forward scan -> byf
    scan_p1<<<B_ * 64, blk256, 0, stream>>>(ba, bbb, chA, chB, HW_, 64, 64, 0);
    scan_p2<<<B_, blk256, 0, stream>>>(chA, chB, chS, 64);
    scan_p3<<<B_ * 64, blk256, 0, stream>>>(ba, bbb, bo_, bu, chS, byf, HW_, 64, 64, 0);
    // backward scan -> byb (gates are flip-invariant: same a/bb/o/u buffers)
    scan_p1<<<B_ * 64, blk256, 0, stream>>>(ba, bbb, chA, chB, HW_, 64, 64, 1);
    scan_p2<<<B_, blk256, 0, stream>>>(chA, chB, chS, 64);
    scan_p3<<<B_ * 64, blk256, 0, stream>>>(ba, bbb, bo_, bu, chS, byb, HW_, 64, 64, 1);

    // ---- rho combine ------------------------------------------------------
    gemm256<<<dim3(B_ * HW_ / 64, 4), blk256, 0, stream>>>(
        bu, byf, byb, 3, Wr, br, nullptr, ba, B_ * HW_, HW_, 0);   // rho_pre -> ba
    combine_rho_k<<<EW, blk256, 0, stream>>>(ba, byf, byb);        // y in ba

    // ---- lam / z ----------------------------------------------------------
    gemm256<<<dim3(B_ * HW_ / 64, 4), blk256, 0, stream>>>(
        ba, bx6, bu, 3, Wgi, bgi, nullptr, bbb, B_ * HW_, HW_, 0); // lam_pre -> bbb
    zfuse_k<<<EW, blk256, 0, stream>>>(ba, bbb, bx6, bo_);         // z -> bo_

    // ---- local depthwise branch ------------------------------------------
    dwconv_k<<<dim3(B_ * C_, 16), blk256, 0, stream>>>(x, dww, dwb, byf);      // vmap -> byf
    transpose_k<<<dim3(HW_ / 32, C_ / 32, B_), blkT, 0, stream>>>(byf, byb, C_, HW_); // vseq -> byb
    gemm256<<<dim3(B_ * HW_ / 64, 4), blk256, 0, stream>>>(
        byb, nullptr, nullptr, 1, Wl, bl, nullptr, bbb, B_ * HW_, HW_, 0);     // v -> bbb
    gemm256<<<dim3(B_ * HW_ / 64, 4), blk256, 0, stream>>>(
        bbb, bo_, nullptr, 2, Wlf, blf, nullptr, byf, B_ * HW_, HW_, 0);       // eta_pre -> byf
    uout_k<<<EW, blk256, 0, stream>>>(byf, bbb, bo_, ba);                      // u_out -> ba

    // ---- output projection + residual ------------------------------------
    gemm256<<<dim3(B_ * HW_ / 64, 4), blk256, 0, stream>>>(
        ba, nullptr, nullptr, 1, Wout, bout, nullptr, byb, B_ * HW_, HW_, 0);  // out_map -> byb
    transpose_add_k<<<dim3(C_ / 32, HW_ / 32, B_), blkT, 0, stream>>>(byb, x, out);
}

// Round 2
// 971.489 us; speedup vs baseline: 1.5336x; 1.5336x over previous
//
#include <hip/hip_runtime.h>
#include <cstddef>

#define B_  8
#define C_  256
#define H_  64
#define W_  64
#define HW_ 4096
#define NG_ 256   // 16x16 global tokens

typedef unsigned short u16;
typedef __attribute__((ext_vector_type(8))) short short8;   // 8 bf16 = 4 VGPRs
typedef __attribute__((ext_vector_type(4))) float f32x4;

__device__ __forceinline__ float sigm(float v) { return 1.f / (1.f + expf(-v)); }

__device__ __forceinline__ u16 f2bf(float f) {
    union { float f; unsigned u; } x; x.f = f;
    unsigned r = x.u + 0x7fff + ((x.u >> 16) & 1);   // RNE
    return (u16)(r >> 16);
}

// ---------------------------------------------------------------------------
// Pre-transpose + bf16-convert the 14 weight seg-matrices:
// Wpre[s][n][k] = bf16(Wsrc[rowoff+k][n]).  grid (8, 8, 14), block (32,8)
// seg order: 0 Wt | 1 Wf | 2 Ww | 3 Wo | 4-6 Wr | 7-9 Wgi | 10 Wl | 11-12 Wlf | 13 Wout
// ---------------------------------------------------------------------------
__global__ __launch_bounds__(256) void prepw_k(
    const float* __restrict__ Wt, const float* __restrict__ Wf, const float* __restrict__ Ww,
    const float* __restrict__ Wo, const float* __restrict__ Wr, const float* __restrict__ Wgi,
    const float* __restrict__ Wl, const float* __restrict__ Wlf, const float* __restrict__ Wout,
    u16* __restrict__ Wpre)
{
    int s = blockIdx.z;
    const float* Wsrc; int rowoff = 0;
    switch (s) {
        case 0: Wsrc = Wt; break;
        case 1: Wsrc = Wf; break;
        case 2: Wsrc = Ww; break;
        case 3: Wsrc = Wo; break;
        case 4: case 5: case 6: Wsrc = Wr;  rowoff = (s - 4) * 256; break;
        case 7: case 8: case 9: Wsrc = Wgi; rowoff = (s - 7) * 256; break;
        case 10: Wsrc = Wl; break;
        case 11: case 12: Wsrc = Wlf; rowoff = (s - 11) * 256; break;
        default: Wsrc = Wout; break;
    }
    __shared__ float t[32][33];
    int k0 = blockIdx.y * 32, n0 = blockIdx.x * 32;
    int tx = threadIdx.x, ty = threadIdx.y;
#pragma unroll
    for (int i = 0; i < 32; i += 8)
        t[ty + i][tx] = Wsrc[(size_t)(rowoff + k0 + ty + i) * 256 + n0 + tx];
    __syncthreads();
    u16* op = Wpre + (size_t)s * 65536;
#pragma unroll
    for (int i = 0; i < 32; i += 8)
        op[(size_t)(n0 + ty + i) * 256 + k0 + tx] = f2bf(t[tx][ty + i]);
}

// ---------------------------------------------------------------------------
// bf16 MFMA GEMM: out[M,256] = sum_seg A_seg[M,256] @ W_seg  (W pre-transposed bf16)
// Tile 128(m) x 128(n), 256 threads = 4 waves, wave computes 64x64 via 4x4 mfma tiles.
// mode 0: + bias[n] | mode 1: + bias[n] + pos[(m%NTOK)*256+n] | mode 2: + bias[(m/NTOK)*256+n]
// ---------------------------------------------------------------------------
#define LDK 80   // padded LDS row stride in bf16 elements (160 B, 16B-aligned)
__global__ __launch_bounds__(256) void gemm_mfma(
    const float* __restrict__ A0, const float* __restrict__ A1, const float* __restrict__ A2,
    int nseg, const u16* __restrict__ Wpre, const float* __restrict__ bias,
    const float* __restrict__ pos, float* __restrict__ out, int M, int NTOK, int mode)
{
    __shared__ u16 Asm[128 * LDK];
    __shared__ u16 Bsm[128 * LDK];
    const int tid = threadIdx.x;
    const int lane = tid & 63, wave = tid >> 6;
    const int wm = wave & 1, wn = wave >> 1;
    const int m0 = blockIdx.x * 128, n0 = blockIdx.y * 128;
    const int l15 = lane & 15, lq = lane >> 4;

    f32x4 acc[4][4] = {};

    const int srow = tid >> 1;          // 0..127
    const int skoff = (tid & 1) * 32;   // 0 or 32

    for (int seg = 0; seg < nseg; ++seg) {
        const float* __restrict__ A = (seg == 0) ? A0 : ((seg == 1) ? A1 : A2);
        const float* arow = A + (size_t)(m0 + srow) * 256 + skoff;
        const u16*   wrow = Wpre + (size_t)seg * 65536 + (size_t)(n0 + srow) * 256 + skoff;

        for (int k0 = 0; k0 < 256; k0 += 64) {
            // ---- stage A (fp32 -> bf16) : 32 elems/thread ----
#pragma unroll
            for (int c = 0; c < 4; ++c) {
                float4 f0 = *(const float4*)(arow + k0 + c * 8);
                float4 f1 = *(const float4*)(arow + k0 + c * 8 + 4);
                short8 v;
                v[0] = (short)f2bf(f0.x); v[1] = (short)f2bf(f0.y);
                v[2] = (short)f2bf(f0.z); v[3] = (short)f2bf(f0.w);
                v[4] = (short)f2bf(f1.x); v[5] = (short)f2bf(f1.y);
                v[6] = (short)f2bf(f1.z); v[7] = (short)f2bf(f1.w);
                *(short8*)(&Asm[srow * LDK + skoff + c * 8]) = v;
            }
            // ---- stage W (already bf16) : 32 elems/thread ----
#pragma unroll
            for (int c = 0; c < 4; ++c)
                *(short8*)(&Bsm[srow * LDK + skoff + c * 8]) =
                    *(const short8*)(wrow + k0 + c * 8);
            __syncthreads();

#pragma unroll
            for (int ks = 0; ks < 2; ++ks) {
                short8 af[4], bfr[4];
#pragma unroll
                for (int i = 0; i < 4; ++i) {
                    int mr = wm * 64 + i * 16 + l15;
                    af[i] = *(const short8*)(&Asm[mr * LDK + ks * 32 + lq * 8]);
                }
#pragma unroll
                for (int j = 0; j < 4; ++j) {
                    int nr = wn * 64 + j * 16 + l15;
                    bfr[j] = *(const short8*)(&Bsm[nr * LDK + ks * 32 + lq * 8]);
                }
#pragma unroll
                for (int i = 0; i < 4; ++i)
#pragma unroll
                    for (int j = 0; j < 4; ++j)
                        acc[i][j] = __builtin_amdgcn_mfma_f32_16x16x32_bf16(
                            af[i], bfr[j], acc[i][j], 0, 0, 0);
            }
            __syncthreads();
        }
    }

    // epilogue: lane holds D[m = quad*4+r][n = l15] per 16x16 tile
#pragma unroll
    for (int i = 0; i < 4; ++i) {
        int mbase = m0 + wm * 64 + i * 16 + lq * 4;
#pragma unroll
        for (int j = 0; j < 4; ++j) {
            int n = n0 + wn * 64 + j * 16 + l15;
#pragma unroll
            for (int r = 0; r < 4; ++r) {
                int m = mbase + r;
                float v = acc[i][j][r];
                if (mode == 0)      v += bias[n];
                else if (mode == 1) v += bias[n] + pos[(size_t)(m % NTOK) * 256 + n];
                else                v += bias[(size_t)(m / NTOK) * 256 + n];
                out[(size_t)m * 256 + n] = v;
            }
        }
    }
}

// ---------------------------------------------------------------------------
// Transpose [B][R][Cc] -> [B][Cc][R].  grid (Cc/32, R/32, B), block (32,8)
// ---------------------------------------------------------------------------
__global__ __launch_bounds__(256) void transpose_k(const float* __restrict__ in,
                                                   float* __restrict__ out, int R, int Cc)
{
    __shared__ float t[32][33];
    int b = blockIdx.z;
    int r0 = blockIdx.y * 32, c0 = blockIdx.x * 32;
    int tx = threadIdx.x, ty = threadIdx.y;
    const float* ip = in + (size_t)b * R * Cc;
    float* op = out + (size_t)b * R * Cc;
#pragma unroll
    for (int k = 0; k < 32; k += 8)
        t[ty + k][tx] = ip[(size_t)(r0 + ty + k) * Cc + c0 + tx];
    __syncthreads();
#pragma unroll
    for (int k = 0; k < 32; k += 8)
        op[(size_t)(c0 + ty + k) * R + r0 + tx] = t[tx][ty + k];
}

// out[B][C][HW] = x + transpose(in [B][HW][C]).  grid (C/32, HW/32, B), block (32,8)
__global__ __launch_bounds__(256) void transpose_add_k(const float* __restrict__ in,
                                                       const float* __restrict__ x,
                                                       float* __restrict__ out)
{
    __shared__ float t[32][33];
    int b = blockIdx.z;
    int r0 = blockIdx.y * 32, c0 = blockIdx.x * 32;  // r = hw, c = channel
    int tx = threadIdx.x, ty = threadIdx.y;
    const float* ip = in + (size_t)b * HW_ * C_;
    const float* xp = x  + (size_t)b * HW_ * C_;
    float* op = out + (size_t)b * HW_ * C_;
#pragma unroll
    for (int k = 0; k < 32; k += 8)
        t[ty + k][tx] = ip[(size_t)(r0 + ty + k) * C_ + c0 + tx];
    __syncthreads();
#pragma unroll
    for (int k = 0; k < 32; k += 8) {
        size_t oi = (size_t)(c0 + ty + k) * HW_ + r0 + tx;
        op[oi] = xp[oi] + t[tx][ty + k];
    }
}

// ---------------------------------------------------------------------------
// 4x4 avg pool x[B][C][64][64] -> seq_g[B][256tok][C].  grid (B, C), block 256 = ghw
// ---------------------------------------------------------------------------
__global__ __launch_bounds__(256) void pool_k(const float* __restrict__ x, float* __restrict__ seqg)
{
    int b = blockIdx.x, c = blockIdx.y, ghw = threadIdx.x;
    int gh = ghw >> 4, gw = ghw & 15;
    const float* xp = x + ((size_t)b * C_ + c) * HW_;
    float s = 0.f;
#pragma unroll
    for (int dy = 0; dy < 4; ++dy)
#pragma unroll
        for (int dx = 0; dx < 4; ++dx)
            s += xp[(gh * 4 + dy) * W_ + gw * 4 + dx];
    seqg[((size_t)b * NG_ + ghw) * C_ + c] = s * (1.f / 16.f);
}

// pos_fine [1][256][32][32] -> posF[4096][256], half-pixel bilinear 2x (clamp == renorm)
__global__ __launch_bounds__(256) void posfine_k(const float* __restrict__ pf, float* __restrict__ posF)
{
    int hw = blockIdx.x, c = threadIdx.x;
    int h = hw >> 6, w = hw & 63;
    float fy = h * 0.5f - 0.25f, fx = w * 0.5f - 0.25f;
    int y0 = (int)floorf(fy); float wy = fy - (float)y0;
    int x0 = (int)floorf(fx); float wx = fx - (float)x0;
    int y0c = min(max(y0, 0), 31), y1c = min(max(y0 + 1, 0), 31);
    int x0c = min(max(x0, 0), 31), x1c = min(max(x0 + 1, 0), 31);
    const float* p = pf + (size_t)c * 1024;
    float v = (1.f - wy) * ((1.f - wx) * p[y0c * 32 + x0c] + wx * p[y0c * 32 + x1c])
            +        wy  * ((1.f - wx) * p[y1c * 32 + x0c] + wx * p[y1c * 32 + x1c]);
    posF[(size_t)hw * C_ + c] = v;
}

// pos_glob [1][256][32][32] -> posG[256][256]: antialiased 2x downsample (4-tap triangle)
__global__ __launch_bounds__(256) void posglob_k(const float* __restrict__ pg, float* __restrict__ posG)
{
    int ghw = blockIdx.x, c = threadIdx.x;
    int gh = ghw >> 4, gw = ghw & 15;
    const float wt[4] = {0.125f, 0.375f, 0.375f, 0.125f};
    float wy[4], wx[4]; int jy[4], jx[4];
    float sy = 0.f, sx = 0.f;
#pragma unroll
    for (int k = 0; k < 4; ++k) {
        jy[k] = 2 * gh - 1 + k; jx[k] = 2 * gw - 1 + k;
        wy[k] = (jy[k] >= 0 && jy[k] < 32) ? wt[k] : 0.f; sy += wy[k];
        wx[k] = (jx[k] >= 0 && jx[k] < 32) ? wt[k] : 0.f; sx += wx[k];
    }
    const float* p = pg + (size_t)c * 1024;
    float acc = 0.f;
#pragma unroll
    for (int ky = 0; ky < 4; ++ky) {
        if (wy[ky] == 0.f) continue;
        float row = 0.f;
#pragma unroll
        for (int kx = 0; kx < 4; ++kx)
            if (wx[kx] != 0.f) row += wx[kx] * p[jy[ky] * 32 + jx[kx]];
        acc += wy[ky] * row;
    }
    posG[(size_t)ghw * C_ + c] = acc / (sy * sx);
}

// y_g[B][256tok][C] -> y_g_seq[B][4096][C]: half-pixel bilinear 4x up (clamp == renorm)
__global__ __launch_bounds__(256) void upsample_k(const float* __restrict__ yg, float* __restrict__ ygs)
{
    int b = blockIdx.x >> 12, hw = blockIdx.x & 4095, c = threadIdx.x;
    int h = hw >> 6, w = hw & 63;
    float fy = h * 0.25f - 0.375f, fx = w * 0.25f - 0.375f;
    int y0 = (int)floorf(fy); float wy = fy - (float)y0;
    int x0 = (int)floorf(fx); float wx = fx - (float)x0;
    int y0c = min(max(y0, 0), 15), y1c = min(max(y0 + 1, 0), 15);
    int x0c = min(max(x0, 0), 15), x1c = min(max(x0 + 1, 0), 15);
    const float* p = yg + (size_t)b * NG_ * C_ + c;
    float v = (1.f - wy) * ((1.f - wx) * p[(y0c * 16 + x0c) * C_] + wx * p[(y0c * 16 + x1c) * C_])
            +        wy  * ((1.f - wx) * p[(y1c * 16 + x0c) * C_] + wx * p[(y1c * 16 + x1c) * C_]);
    ygs[((size_t)b * HW_ + hw) * C_ + c] = v;
}

// depthwise 3x3 SAME conv + bias -> vmap[B][C][HW].  grid (B*C, 16), block 256
__global__ __launch_bounds__(256) void dwconv_k(const float* __restrict__ x,
                                                const float* __restrict__ dww,
                                                const float* __restrict__ dwb,
                                                float* __restrict__ vmap)
{
    int bc = blockIdx.x;
    int hw = blockIdx.y * 256 + threadIdx.x;
    int c = bc & 255;
    int h = hw >> 6, w = hw & 63;
    const float* xp = x + (size_t)bc * HW_;
    const float* wp = dww + c * 9;
    float acc = dwb[c];
#pragma unroll
    for (int dy = 0; dy < 3; ++dy) {
        int hh = h + dy - 1;
        if (hh < 0 || hh > 63) continue;
#pragma unroll
        for (int dx = 0; dx < 3; ++dx) {
            int ww = w + dx - 1;
            if (ww < 0 || ww > 63) continue;
            acc += xp[hh * W_ + ww] * wp[dy * 3 + dx];
        }
    }
    vmap[(size_t)bc * HW_ + hw] = acc;
}

// partial token-mean: grid (B, S), block 256=c
__global__ __launch_bounds__(256) void meanpart_k(const float* __restrict__ u, float* __restrict__ part,
                                                  int Ntok, int chunkLen)
{
    int b = blockIdx.x, s = blockIdx.y, c = threadIdx.x;
    float acc = 0.f;
    for (int i = 0; i < chunkLen; ++i) {
        int t = s * chunkLen + i;
        acc += u[((size_t)b * Ntok + t) * C_ + c];
    }
    part[((size_t)b * gridDim.y + s) * C_ + c] = acc;
}

// finish mean + LayerNorm over C.  grid (B), block 256
__global__ __launch_bounds__(256) void ln_k(const float* __restrict__ part, int S, float invN,
                                            const float* __restrict__ g, const float* __restrict__ bta,
                                            float* __restrict__ cout)
{
    __shared__ float red[256];
    int c = threadIdx.x, b = blockIdx.x;
    float v = 0.f;
    for (int s = 0; s < S; ++s) v += part[((size_t)b * S + s) * C_ + c];
    v *= invN;
    red[c] = v; __syncthreads();
    for (int st = 128; st > 0; st >>= 1) { if (c < st) red[c] += red[c + st]; __syncthreads(); }
    float m = red[0] * (1.f / 256.f);
    __syncthreads();
    float d = v - m;
    red[c] = d * d; __syncthreads();
    for (int st = 128; st > 0; st >>= 1) { if (c < st) red[c] += red[c + st]; __syncthreads(); }
    float var = red[0] * (1.f / 256.f);
    cout[(size_t)b * C_ + c] = d * rsqrtf(var + 1e-5f) * g[c] + bta[c];
}

// per-batch gate bias rows: cf[gate][b][n] = c[b] @ Wg[256:,:] + bg.  grid (B, 3), block 256
__global__ __launch_bounds__(256) void gatebias_k(const float* __restrict__ cvec,
    const float* __restrict__ Wf, const float* __restrict__ bf,
    const float* __restrict__ Ww, const float* __restrict__ bw,
    const float* __restrict__ Wo, const float* __restrict__ bo,
    float* __restrict__ outb)
{
    int n = threadIdx.x, b = blockIdx.x, gate = blockIdx.y;
    const float* Wm = (gate == 0) ? Wf : ((gate == 1) ? Ww : Wo);
    const float* bi = (gate == 0) ? bf : ((gate == 1) ? bw : bo);
    __shared__ float cs[256];
    cs[n] = cvec[(size_t)b * C_ + n];
    __syncthreads();
    float acc = bi[n];
    for (int k = 0; k < 256; ++k)
        acc += cs[k] * Wm[(size_t)(256 + k) * C_ + n];
    outb[((size_t)gate * B_ + b) * C_ + n] = acc;
}

// gate activations in place: a = sigmoid(-dpre); bb = (1-a)*sigmoid(wpre)*u; o = sigmoid(opre)
__global__ __launch_bounds__(256) void gates_k(float* __restrict__ dpre, float* __restrict__ wpre,
                                               float* __restrict__ opre, const float* __restrict__ u)
{
    size_t i = (size_t)blockIdx.x * 256 + threadIdx.x;
    float d = dpre[i], wv = wpre[i], ov = opre[i], uv = u[i];
    float a = 1.f / (1.f + expf(d));          // exp(-softplus(d)) == sigmoid(-d)
    float g = sigm(wv);
    dpre[i] = a;
    wpre[i] = (1.f - a) * g * uv;
    opre[i] = sigm(ov);
}

// ---------------- chunked linear-recurrence scan -------------------------
__global__ __launch_bounds__(256) void scan_p1(const float* __restrict__ a, const float* __restrict__ bb,
                                               float* __restrict__ Ab, float* __restrict__ Bb,
                                               int Ntok, int chunkLen, int nchunk, int backward)
{
    int c = threadIdx.x;
    int chunk = blockIdx.x % nchunk;
    int b = blockIdx.x / nchunk;
    float sA = 1.f, sB = 0.f;
    for (int i = 0; i < chunkLen; ++i) {
        int tp = chunk * chunkLen + i;
        int t = backward ? (Ntok - 1 - tp) : tp;
        size_t idx = ((size_t)b * Ntok + t) * C_ + c;
        float av = a[idx];
        sB = av * sB + bb[idx];
        sA *= av;
    }
    size_t o = ((size_t)b * nchunk + chunk) * C_ + c;
    Ab[o] = sA; Bb[o] = sB;
}

__global__ __launch_bounds__(256) void scan_p2(const float* __restrict__ Ab, const float* __restrict__ Bb,
                                               float* __restrict__ Sb, int nchunk)
{
    int c = threadIdx.x, b = blockIdx.x;
    float s = 0.f;
    for (int ch = 0; ch < nchunk; ++ch) {
        size_t o = ((size_t)b * nchunk + ch) * C_ + c;
        Sb[o] = s;
        s = Ab[o] * s + Bb[o];
    }
}

__global__ __launch_bounds__(256) void scan_p3(const float* __restrict__ a, const float* __restrict__ bb,
                                               const float* __restrict__ o_, const float* __restrict__ u,
                                               const float* __restrict__ Sb, float* __restrict__ y,
                                               int Ntok, int chunkLen, int nchunk, int backward)
{
    int c = threadIdx.x;
    int chunk = blockIdx.x % nchunk;
    int b = blockIdx.x / nchunk;
    float s = Sb[((size_t)b * nchunk + chunk) * C_ + c];
    for (int i = 0; i < chunkLen; ++i) {
        int tp = chunk * chunkLen + i;
        int t = backward ? (Ntok - 1 - tp) : tp;
        size_t idx = ((size_t)b * Ntok + t) * C_ + c;
        float av = a[idx];
        s = av * s + bb[idx];
        float ov = o_[idx];
        y[idx] = ov * s + (1.f - ov) * u[idx];
    }
}

// ---------------- elementwise combiners ----------------------------------
__global__ __launch_bounds__(256) void combine_rho_k(float* __restrict__ rho_y,
                                                     const float* __restrict__ yf,
                                                     const float* __restrict__ yb)
{
    size_t i = (size_t)blockIdx.x * 256 + threadIdx.x;
    float r = sigm(rho_y[i]);
    rho_y[i] = r * yf[i] + (1.f - r) * yb[i];
}

__global__ __launch_bounds__(256) void zfuse_k(const float* __restrict__ y, const float* __restrict__ lam,
                                               const float* __restrict__ ygs, float* __restrict__ z)
{
    size_t i = (size_t)blockIdx.x * 256 + threadIdx.x;
    z[i] = y[i] + sigm(lam[i]) * ygs[i];
}

__global__ __launch_bounds__(256) void uout_k(const float* __restrict__ eta, const float* __restrict__ v,
                                              const float* __restrict__ z, float* __restrict__ uo)
{
    size_t i = (size_t)blockIdx.x * 256 + threadIdx.x;
    float e = sigm(eta[i]);
    uo[i] = e * v[i] + (1.f - e) * z[i];
}

// ===========================================================================
extern "C" void kernel_launch(void* const* d_in, const int* in_sizes, int n_in,
                              void* d_out, int out_size, void* d_ws, size_t ws_size,
                              hipStream_t stream)
{
    const float* x        = (const float*)d_in[0];
    const float* Wt       = (const float*)d_in[1];
    const float* bt       = (const float*)d_in[2];
    const float* pos_fine = (const float*)d_in[3];
    const float* pos_glob = (const float*)d_in[4];
    const float* ln_g     = (const float*)d_in[5];
    const float* ln_b     = (const float*)d_in[6];
    const float* Wf       = (const float*)d_in[7];
    const float* bf       = (const float*)d_in[8];
    const float* Ww       = (const float*)d_in[9];
    const float* bw       = (const float*)d_in[10];
    const float* Wo       = (const float*)d_in[11];
    const float* bo       = (const float*)d_in[12];
    const float* Wr       = (const float*)d_in[13];
    const float* br       = (const float*)d_in[14];
    const float* Wgi      = (const float*)d_in[15];
    const float* bgi      = (const float*)d_in[16];
    const float* dww      = (const float*)d_in[17];
    const float* dwb      = (const float*)d_in[18];
    const float* Wl       = (const float*)d_in[19];
    const float* bl       = (const float*)d_in[20];
    const float* Wlf      = (const float*)d_in[21];
    const float* blf      = (const float*)d_in[22];
    const float* Wout     = (const float*)d_in[23];
    const float* bout     = (const float*)d_in[24];
    float* out = (float*)d_out;

    float* w = (float*)d_ws;
    const size_t BNC = (size_t)B_ * HW_ * C_;        // 8,388,608 floats
    float* bu  = w + 0 * BNC;   // u
    float* ba  = w + 1 * BNC;   // dpre -> a -> rho_pre -> y -> u_out
    float* bbb = w + 2 * BNC;   // wpre -> bb -> lam_pre -> v
    float* bo_ = w + 3 * BNC;   // opre -> o -> z
    float* byf = w + 4 * BNC;   // y_f -> vmap -> eta_pre
    float* byb = w + 5 * BNC;   // y_b -> vseq -> out_map staging
    float* bx6 = w + 6 * BNC;   // seq -> y_g_seq
    float* ext = w + 7 * BNC;
    float* posF = ext;  ext += (size_t)HW_ * C_;
    float* posG = ext;  ext += (size_t)NG_ * C_;
    float* part = ext;  ext += (size_t)B_ * 32 * C_;
    float* cln  = ext;  ext += (size_t)B_ * C_;
    float* cf   = ext;  ext += (size_t)3 * B_ * C_;
    float* seqg = ext;  ext += (size_t)B_ * NG_ * C_;
    float* ug   = ext;  ext += (size_t)B_ * NG_ * C_;
    float* ag   = ext;  ext += (size_t)B_ * NG_ * C_;
    float* bbg  = ext;  ext += (size_t)B_ * NG_ * C_;
    float* og   = ext;  ext += (size_t)B_ * NG_ * C_;
    float* ygt  = ext;  ext += (size_t)B_ * NG_ * C_;
    float* chA  = ext;  ext += (size_t)B_ * 64 * C_;
    float* chB  = ext;  ext += (size_t)B_ * 64 * C_;
    float* chS  = ext;  ext += (size_t)B_ * 64 * C_;
    u16* Wpre = (u16*)ext;      // 14 * 65536 bf16 = 1.75 MiB

    const dim3 blk256(256);
    const dim3 blkT(32, 8);
    const int EW = (int)(BNC / 256);       // 32768 elementwise blocks
    const int EWG = (B_ * NG_ * C_) / 256; // 2048
    const dim3 gBig(B_ * HW_ / 128, 2);    // 256 x 2 blocks
    const dim3 gSml(B_ * NG_ / 128, 2);    // 16 x 2 blocks
    const size_t WS = 65536;               // bf16 elems per weight seg

    // ---- weight prep ------------------------------------------------------
    prepw_k<<<dim3(8, 8, 14), blkT, 0, stream>>>(Wt, Wf, Ww, Wo, Wr, Wgi, Wl, Wlf, Wout, Wpre);

    // ---- fine: seq + u ----------------------------------------------------
    transpose_k<<<dim3(HW_ / 32, C_ / 32, B_), blkT, 0, stream>>>(x, bx6, C_, HW_);
    posfine_k<<<HW_, blk256, 0, stream>>>(pos_fine, posF);
    gemm_mfma<<<gBig, blk256, 0, stream>>>(
        bx6, nullptr, nullptr, 1, Wpre + 0 * WS, bt, posF, bu, B_ * HW_, HW_, 1);

    // ---- global branch ----------------------------------------------------
    pool_k<<<dim3(B_, C_), blk256, 0, stream>>>(x, seqg);
    posglob_k<<<NG_, blk256, 0, stream>>>(pos_glob, posG);
    gemm_mfma<<<gSml, blk256, 0, stream>>>(
        seqg, nullptr, nullptr, 1, Wpre + 0 * WS, bt, posG, ug, B_ * NG_, NG_, 1);
    meanpart_k<<<dim3(B_, 8), blk256, 0, stream>>>(ug, part, NG_, 32);
    ln_k<<<B_, blk256, 0, stream>>>(part, 8, 1.f / NG_, ln_g, ln_b, cln);
    gatebias_k<<<dim3(B_, 3), blk256, 0, stream>>>(cln, Wf, bf, Ww, bw, Wo, bo, cf);
    gemm_mfma<<<gSml, blk256, 0, stream>>>(
        ug, nullptr, nullptr, 1, Wpre + 1 * WS, cf + 0 * B_ * C_, nullptr, ag, B_ * NG_, NG_, 2);
    gemm_mfma<<<gSml, blk256, 0, stream>>>(
        ug, nullptr, nullptr, 1, Wpre + 2 * WS, cf + 1 * B_ * C_, nullptr, bbg, B_ * NG_, NG_, 2);
    gemm_mfma<<<gSml, blk256, 0, stream>>>(
        ug, nullptr, nullptr, 1, Wpre + 3 * WS, cf + 2 * B_ * C_, nullptr, og, B_ * NG_, NG_, 2);
    gates_k<<<EWG, blk256, 0, stream>>>(ag, bbg, og, ug);
    scan_p1<<<B_ * 16, blk256, 0, stream>>>(ag, bbg, chA, chB, NG_, 16, 16, 0);
    scan_p2<<<B_, blk256, 0, stream>>>(chA, chB, chS, 16);
    scan_p3<<<B_ * 16, blk256, 0, stream>>>(ag, bbg, og, ug, chS, ygt, NG_, 16, 16, 0);
    upsample_k<<<B_ * HW_, blk256, 0, stream>>>(ygt, bx6);   // y_g_seq -> bx6

    // ---- fine: gates + bidirectional scans -------------------------------
    meanpart_k<<<dim3(B_, 32), blk256, 0, stream>>>(bu, part, HW_, 128);
    ln_k<<<B_, blk256, 0, stream>>>(part, 32, 1.f / HW_, ln_g, ln_b, cln);
    gatebias_k<<<dim3(B_, 3), blk256, 0, stream>>>(cln, Wf, bf, Ww, bw, Wo, bo, cf);
    gemm_mfma<<<gBig, blk256, 0, stream>>>(
        bu, nullptr, nullptr, 1, Wpre + 1 * WS, cf + 0 * B_ * C_, nullptr, ba, B_ * HW_, HW_, 2);
    gemm_mfma<<<gBig, blk256, 0, stream>>>(
        bu, nullptr, nullptr, 1, Wpre + 2 * WS, cf + 1 * B_ * C_, nullptr, bbb, B_ * HW_, HW_, 2);
    gemm_mfma<<<gBig, blk256, 0, stream>>>(
        bu, nullptr, nullptr, 1, Wpre + 3 * WS, cf + 2 * B_ * C_, nullptr, bo_, B_ * HW_, HW_, 2);
    gates_k<<<EW, blk256, 0, stream>>>(ba, bbb, bo_, bu);
    // forward scan -> byf
    scan_p1<<<B_ * 64, blk256, 0, stream>>>(ba, bbb, chA, chB, HW_, 64, 64, 0);
    scan_p2<<<B_, blk256, 0, stream>>>(chA, chB, chS, 64);
    scan_p3<<<B_ * 64, blk256, 0, stream>>>(ba, bbb, bo_, bu, chS, byf, HW_, 64, 64, 0);
    // backward scan -> byb (gates flip-invariant: same buffers)
    scan_p1<<<B_ * 64, blk256, 0, stream>>>(ba, bbb, chA, chB, HW_, 64, 64, 1);
    scan_p2<<<B_, blk256, 0, stream>>>(chA, chB, chS, 64);
    scan_p3<<<B_ * 64, blk256, 0, stream>>>(ba, bbb, bo_, bu, chS, byb, HW_, 64, 64, 1);

    // ---- rho combine ------------------------------------------------------
    gemm_mfma<<<gBig, blk256, 0, stream>>>(
        bu, byf, byb, 3, Wpre + 4 * WS, br, nullptr, ba, B_ * HW_, HW_, 0);   // rho_pre -> ba
    combine_rho_k<<<EW, blk256, 0, stream>>>(ba, byf, byb);                   // y in ba

    // ---- lam / z ----------------------------------------------------------
    gemm_mfma<<<gBig, blk256, 0, stream>>>(
        ba, bx6, bu, 3, Wpre + 7 * WS, bgi, nullptr, bbb, B_ * HW_, HW_, 0);  // lam_pre -> bbb
    zfuse_k<<<EW, blk256, 0, stream>>>(ba, bbb, bx6, bo_);                    // z -> bo_

    // ---- local depthwise branch ------------------------------------------
    dwconv_k<<<dim3(B_ * C_, 16), blk256, 0, stream>>>(x, dww, dwb, byf);     // vmap -> byf
    transpose_k<<<dim3(HW_ / 32, C_ / 32, B_), blkT, 0, stream>>>(byf, byb, C_, HW_); // vseq
    gemm_mfma<<<gBig, blk256, 0, stream>>>(
        byb, nullptr, nullptr, 1, Wpre + 10 * WS, bl, nullptr, bbb, B_ * HW_, HW_, 0);   // v
    gemm_mfma<<<gBig, blk256, 0, stream>>>(
        bbb, bo_, nullptr, 2, Wpre + 11 * WS, blf, nullptr, byf, B_ * HW_, HW_, 0);      // eta_pre
    uout_k<<<EW, blk256, 0, stream>>>(byf, bbb, bo_, ba);                     // u_out -> ba

    // ---- output projection + residual ------------------------------------
    gemm_mfma<<<gBig, blk256, 0, stream>>>(
        ba, nullptr, nullptr, 1, Wpre + 13 * WS, bout, nullptr, byb, B_ * HW_, HW_, 0);  // out_map
    transpose_add_k<<<dim3(C_ / 32, HW_ / 32, B_), blkT, 0, stream>>>(byb, x, out);
}